// Round 3
// baseline (386.495 us; speedup 1.0000x reference)
//
#include <hip/hip_runtime.h>

#define NN 4096

// ws layout (float offsets)
#define OFF_G   0
#define OFF_S   4096
#define OFF_GS  (OFF_S + 64*4096)        // raw-k 32-row group sums [64 heads][128 groups][64]
#define OFF_KP  (OFF_GS + 64*128*64)     // exclusive group prefixes [64][128][64]

// ---------------- Kernel A: G = P^T P  (P is [64,64]) ----------------
__global__ void kA_gram(const float* __restrict__ P, float* __restrict__ G) {
    int i = blockIdx.x;      // 0..63
    int j = threadIdx.x;     // 0..63
    float acc = 0.f;
    for (int m = 0; m < 64; ++m)
        acc += P[m*64 + i] * P[m*64 + j];
    G[i*64 + j] = acc;
}

// ------- Kernel B: per (head, 256-row chunk): S += K^T V (8x8 tiles) + raw-k group sums -------
__launch_bounds__(256, 4)
__global__ void kB(const float* __restrict__ k, const float* __restrict__ v,
                   float* __restrict__ S, float* __restrict__ gs) {
    __shared__ __align__(16) float kt[64*68];   // 64 rows, float4-stride 17
    __shared__ __align__(16) float vt[64*68];

    int t = threadIdx.x;
    int head = blockIdx.y, chunk = blockIdx.x;
    long base = ((long)head*NN + (long)chunk*256) * 64;

    int tg = t >> 6, l = t & 63;
    int dg = l >> 3, eg = l & 7;        // 8x8 tile: S rows dg*8.., cols eg*8..
    float acc[8][8] = {};

    float4* kt4 = (float4*)kt;
    float4* vt4 = (float4*)vt;

    for (int tile = 0; tile < 4; ++tile) {
        __syncthreads();  // protect kt/vt from previous iteration's readers
        const float4* kgl = (const float4*)(k + base + (long)tile*64*64);
        const float4* vgl = (const float4*)(v + base + (long)tile*64*64);
#pragma unroll
        for (int i = 0; i < 4; ++i) {
            int f = t + 256*i;            // 0..1023 : row=f>>4, colquad=f&15
            int r = f >> 4, c = f & 15;
            kt4[r*17 + c] = kgl[f];
            vt4[r*17 + c] = vgl[f];
        }
        __syncthreads();

        // ---- S accumulation: rows tg*16 .. tg*16+15 of this 64-row tile ----
#pragma unroll 4
        for (int rr = 0; rr < 16; ++rr) {
            int r = tg*16 + rr;
            float4 ka = kt4[r*17 + dg*2];
            float4 kb = kt4[r*17 + dg*2 + 1];
            float4 va = vt4[r*17 + eg*2];
            float4 vb = vt4[r*17 + eg*2 + 1];
            float kk8[8] = {ka.x,ka.y,ka.z,ka.w,kb.x,kb.y,kb.z,kb.w};
            float vv8[8] = {va.x,va.y,va.z,va.w,vb.x,vb.y,vb.z,vb.w};
#pragma unroll
            for (int i = 0; i < 8; ++i)
#pragma unroll
                for (int j = 0; j < 8; ++j)
                    acc[i][j] += kk8[i]*vv8[j];
        }

        // ---- raw-k 32-row group sums (2 groups per 64-row tile) ----
        if (t < 128) {
            int wv = t >> 6, m = t & 63;
            float s = 0.f;
#pragma unroll 8
            for (int r2 = 0; r2 < 32; ++r2) s += kt[(wv*32 + r2)*68 + m];
            gs[((long)head*128 + chunk*8 + tile*2 + wv)*64 + m] = s;
        }
    }

    // ---- cross-group LDS reduction, then one atomic per S element ----
    // Writer: lane l stores acc element x at rotated LDS col (x+l)&63.
    // Reader MUST decode (i,j) from x, not from the rotated position.
    __syncthreads();
    float* buf = (tg & 1) ? vt : kt;   // tg0,2 -> kt ; tg1,3 -> vt
    if (tg < 2) {
#pragma unroll
        for (int x = 0; x < 64; ++x)
            buf[l*68 + ((x + l) & 63)] = acc[x >> 3][x & 7];
    }
    __syncthreads();
    if (tg >= 2) {
#pragma unroll
        for (int x = 0; x < 64; ++x)
            buf[l*68 + ((x + l) & 63)] += acc[x >> 3][x & 7];
    }
    __syncthreads();
    if (tg == 0) {
#pragma unroll
        for (int x = 0; x < 64; ++x) {
            int xi = (x + l) & 63;
            float vsum = kt[l*68 + xi] + vt[l*68 + xi];
            int i = x >> 3, j = x & 7;   // decode from x (rotation-corrected)
            atomicAdd(&S[head*4096 + (dg*8 + i)*64 + eg*8 + j], vsum);
        }
    }
}

// ------- Kernel C: per head: exclusive scan of group sums -> kpre -------
__launch_bounds__(256)
__global__ void kC(const float* __restrict__ gs, float* __restrict__ kpre) {
    __shared__ __align__(16) float gL[128*68];
    int t = threadIdx.x;
    int head = blockIdx.x;

    const float4* gs4 = (const float4*)(gs + (long)head*128*64);
    float4* gL4 = (float4*)gL;
#pragma unroll
    for (int i = 0; i < 8; ++i) {
        int f = t + 256*i;              // 0..2047
        int r = f >> 4, c = f & 15;
        gL4[r*17 + c] = gs4[f];
    }
    __syncthreads();

    if (t < 64) {
        float run = 0.f;
        for (int g = 0; g < 128; ++g) {
            kpre[((long)head*128 + g)*64 + t] = run;
            run += gL[g*68 + t];
        }
    }
}

// ------- Kernel D: qg = q@G ; denom = qg . (kpre + cumsum k) ; out = (qg*dinv) @ S -------
__launch_bounds__(256, 2)
__global__ void kD(const float* __restrict__ q, const float* __restrict__ k,
                   const float* __restrict__ G, const float* __restrict__ S,
                   const float* __restrict__ kpre, float* __restrict__ out) {
    __shared__ __align__(16) float buf0[128*64];  // q, then k (cumsum'd in place)
    __shared__ __align__(16) float qgs[128*64];
    __shared__ __align__(16) float gsb[64*64];    // G, then S

    int t = threadIdx.x;
    int w = t >> 6, lane = t & 63;
    int head = blockIdx.y, tile = blockIdx.x;     // 32 tiles of 128 rows
    long rowbase = (long)head*NN + (long)tile*128;

    int rg = t >> 3;            // 0..31 -> rows rg*4..rg*4+3
    int cg = t & 7;             // cols cg*8..cg*8+7
    int lrg = (t >> 3) & 7;     // within-wave row group (bank rotation)

    float4* buf04 = (float4*)buf0;
    float4* qgs4  = (float4*)qgs;
    float4* gsb4  = (float4*)gsb;

    // ---- phase 1: stage q tile + G ----
    const float4* qgl = (const float4*)(q + rowbase*64);
#pragma unroll
    for (int i = 0; i < 8; ++i) buf04[t + 256*i] = qgl[t + 256*i];
    const float4* Ggl = (const float4*)G;
#pragma unroll
    for (int i = 0; i < 4; ++i) gsb4[t + 256*i] = Ggl[t + 256*i];
    __syncthreads();

    // ---- phase 2: qg = q @ G  (4x8 per lane, kk rotated by 4*lrg) ----
    {
        float a2[4][8] = {};
        for (int kk0 = 0; kk0 < 64; ++kk0) {
            int kk = (kk0 + 4*lrg) & 63;
            float4 b0 = gsb4[kk*16 + cg*2];
            float4 b1 = gsb4[kk*16 + cg*2 + 1];
            float bb[8] = {b0.x,b0.y,b0.z,b0.w,b1.x,b1.y,b1.z,b1.w};
#pragma unroll
            for (int i = 0; i < 4; ++i) {
                float av = buf0[(rg*4 + i)*64 + kk];
#pragma unroll
                for (int j = 0; j < 8; ++j) a2[i][j] += av*bb[j];
            }
        }
#pragma unroll
        for (int i = 0; i < 4; ++i) {
            qgs4[(rg*4 + i)*16 + cg*2]     = make_float4(a2[i][0],a2[i][1],a2[i][2],a2[i][3]);
            qgs4[(rg*4 + i)*16 + cg*2 + 1] = make_float4(a2[i][4],a2[i][5],a2[i][6],a2[i][7]);
        }
    }
    __syncthreads();

    // ---- phase 3: stage k tile (overwrites q) + S (overwrites G), kpre -> reg ----
    const float4* kgl = (const float4*)(k + rowbase*64);
#pragma unroll
    for (int i = 0; i < 8; ++i) buf04[t + 256*i] = kgl[t + 256*i];
    const float4* Sgl = (const float4*)(S + head*4096);
#pragma unroll
    for (int i = 0; i < 4; ++i) gsb4[t + 256*i] = Sgl[t + 256*i];
    float pre = kpre[((long)head*128 + tile*4 + w)*64 + lane];
    __syncthreads();

    // ---- phase 4: in-place cumsum of k rows, wave w owns 32-row group w ----
    {
        float c = pre;
#pragma unroll 4
        for (int r = 0; r < 32; ++r) {
            int idx = (w*32 + r)*64 + lane;
            c += buf0[idx];
            buf0[idx] = c;
        }
    }
    __syncthreads();

    // ---- phase 5: denom per row; scale qgs row by 1/denom in place ----
    if (t < 128) {
        float d = 0.f;
#pragma unroll 8
        for (int m0 = 0; m0 < 64; ++m0) {
            int m = (m0 + t) & 63;
            d += qgs[t*64 + m] * buf0[t*64 + m];
        }
        float dinv = __builtin_amdgcn_rcpf(d);
#pragma unroll 8
        for (int m0 = 0; m0 < 64; ++m0) {
            int m = (m0 + t) & 63;
            qgs[t*64 + m] *= dinv;
        }
    }
    __syncthreads();

    // ---- phase 6: out = qg' @ S  (4x8 per lane, same rotation) ----
    {
        float o[4][8] = {};
        for (int kk0 = 0; kk0 < 64; ++kk0) {
            int kk = (kk0 + 4*lrg) & 63;
            float4 b0 = gsb4[kk*16 + cg*2];
            float4 b1 = gsb4[kk*16 + cg*2 + 1];
            float bb[8] = {b0.x,b0.y,b0.z,b0.w,b1.x,b1.y,b1.z,b1.w};
#pragma unroll
            for (int i = 0; i < 4; ++i) {
                float av = qgs[(rg*4 + i)*64 + kk];
#pragma unroll
                for (int j = 0; j < 8; ++j) o[i][j] += av*bb[j];
            }
        }
        float4* out4 = (float4*)out;
#pragma unroll
        for (int i = 0; i < 4; ++i) {
            long r = rowbase + rg*4 + i;
            out4[r*16 + cg*2]     = make_float4(o[i][0],o[i][1],o[i][2],o[i][3]);
            out4[r*16 + cg*2 + 1] = make_float4(o[i][4],o[i][5],o[i][6],o[i][7]);
        }
    }
}

extern "C" void kernel_launch(void* const* d_in, const int* in_sizes, int n_in,
                              void* d_out, int out_size, void* d_ws, size_t ws_size,
                              hipStream_t stream) {
    (void)in_sizes; (void)n_in; (void)out_size; (void)ws_size;
    const float* q = (const float*)d_in[0];
    const float* k = (const float*)d_in[1];
    const float* v = (const float*)d_in[2];
    const float* P = (const float*)d_in[3];
    float* out = (float*)d_out;
    float* ws  = (float*)d_ws;

    float* G    = ws + OFF_G;
    float* S    = ws + OFF_S;
    float* gs   = ws + OFF_GS;
    float* kpre = ws + OFF_KP;

    hipMemsetAsync(S, 0, (size_t)64*4096*sizeof(float), stream);
    kA_gram<<<64, 64, 0, stream>>>(P, G);
    kB<<<dim3(16, 64), 256, 0, stream>>>(k, v, S, gs);
    kC<<<64, 256, 0, stream>>>(gs, kpre);
    kD<<<dim3(32, 64), 256, 0, stream>>>(q, k, G, S, kpre, out);
}

// Round 4
// 306.256 us; speedup vs baseline: 1.2620x; 1.2620x over previous
//
#include <hip/hip_runtime.h>

#define NN 4096

// ws layout (float offsets)
#define OFF_G   0
#define OFF_S   4096
#define OFF_GS  (OFF_S + 64*4096)        // raw-k 32-row group sums [64 heads][128 groups][64]
#define OFF_KP  (OFF_GS + 64*128*64)     // exclusive group prefixes [64][128][64]

// ---------------- Kernel A: G = P^T P  (P is [64,64]) ----------------
__global__ void kA_gram(const float* __restrict__ P, float* __restrict__ G) {
    int i = blockIdx.x;      // 0..63
    int j = threadIdx.x;     // 0..63
    float acc = 0.f;
    for (int m = 0; m < 64; ++m)
        acc += P[m*64 + i] * P[m*64 + j];
    G[i*64 + j] = acc;
}

// ------- Kernel B: per (head, 256-row chunk): S += K^T V + raw-k 32-row group sums -------
// Lane j holds S column j in registers (Scol[64]); k rows arrive as LDS broadcasts.
// Waves are independent until the tail (each wave stages/reads only its own 16 rows).
__launch_bounds__(256)
__global__ void kB(const float* __restrict__ k, const float* __restrict__ v,
                   float* __restrict__ S, float* __restrict__ gs) {
    __shared__ __align__(16) float kt[64*64];   // 16 KB, no padding (broadcast + lane-consecutive only)
    __shared__ __align__(16) float vt[64*64];   // 16 KB
    __shared__ float gsb[16*64];                // 16 half-group (16-row) k sums

    int t = threadIdx.x, w = t >> 6, lane = t & 63;
    int head = blockIdx.y, chunk = blockIdx.x;
    long base = ((long)head*NN + (long)chunk*256) * 64;

    float Scol[64];
#pragma unroll
    for (int i = 0; i < 64; ++i) Scol[i] = 0.f;

    for (int s = 0; s < 4; ++s) {
        // stage own 16 rows of k and v (wave-private slice, no barrier needed)
        const float4* kg4 = (const float4*)(k + base + (long)s*4096 + w*1024);
        const float4* vg4 = (const float4*)(v + base + (long)s*4096 + w*1024);
        float4* kl4 = (float4*)&kt[w*1024];
        float4* vl4 = (float4*)&vt[w*1024];
#pragma unroll
        for (int c = 0; c < 4; ++c) {
            kl4[c*64 + lane] = kg4[c*64 + lane];
            vl4[c*64 + lane] = vg4[c*64 + lane];
        }

        // 16-row k half-sum for this wave (feeds the 32-row group sums)
        float hs = 0.f;
#pragma unroll
        for (int r = 0; r < 16; ++r) hs += kt[(w*16 + r)*64 + lane];
        gsb[(s*4 + w)*64 + lane] = hs;

        // S accumulation: Scol[i] += k[r][i] * v[r][lane]
#pragma unroll
        for (int r = 0; r < 16; ++r) {
            float vv = vt[(w*16 + r)*64 + lane];
            const float4* krow = (const float4*)&kt[(w*16 + r)*64];
#pragma unroll
            for (int kq = 0; kq < 16; ++kq) {
                float4 kx = krow[kq];           // wave-uniform broadcast read
                Scol[4*kq+0] += kx.x * vv;
                Scol[4*kq+1] += kx.y * vv;
                Scol[4*kq+2] += kx.z * vv;
                Scol[4*kq+3] += kx.w * vv;
            }
        }
    }
    __syncthreads();

    // gs: combine 16-row halves into 32-row groups (8 groups per chunk)
#pragma unroll
    for (int e = t; e < 512; e += 256) {
        int g = e >> 6, c = e & 63;
        gs[((long)head*128 + chunk*8 + g)*64 + c] = gsb[(2*g)*64 + c] + gsb[(2*g+1)*64 + c];
    }

    // 4-phase cross-wave reduction of Scol into kt, then atomics
    if (w == 0) {
#pragma unroll
        for (int i = 0; i < 64; ++i) kt[i*64 + lane] = Scol[i];
    }
    __syncthreads();
    if (w == 1) {
#pragma unroll
        for (int i = 0; i < 64; ++i) kt[i*64 + lane] += Scol[i];
    }
    __syncthreads();
    if (w == 2) {
#pragma unroll
        for (int i = 0; i < 64; ++i) kt[i*64 + lane] += Scol[i];
    }
    __syncthreads();
    if (w == 3) {
#pragma unroll
        for (int i = 0; i < 64; ++i) kt[i*64 + lane] += Scol[i];
    }
    __syncthreads();
#pragma unroll
    for (int e = t; e < 4096; e += 256)
        atomicAdd(&S[head*4096 + e], kt[e]);
}

// ------- Kernel C: per head: exclusive scan of group sums -> kpre -------
__launch_bounds__(256)
__global__ void kC(const float* __restrict__ gs, float* __restrict__ kpre) {
    __shared__ __align__(16) float gL[128*68];
    int t = threadIdx.x;
    int head = blockIdx.x;

    const float4* gs4 = (const float4*)(gs + (long)head*128*64);
    float4* gL4 = (float4*)gL;
#pragma unroll
    for (int i = 0; i < 8; ++i) {
        int f = t + 256*i;              // 0..2047
        int r = f >> 4, c = f & 15;
        gL4[r*17 + c] = gs4[f];
    }
    __syncthreads();

    if (t < 64) {
        float run = 0.f;
        for (int g = 0; g < 128; ++g) {
            kpre[((long)head*128 + g)*64 + t] = run;
            run += gL[g*68 + t];
        }
    }
}

// ------- Kernel D: qg = q@G ; denom = qg . kcum ; out = (qg @ S) * dinv -------
// Wave-independent: each wave owns 16 rows; lane j owns column j.
// B-matrices (G, S) live in registers as 32-row half-columns; A arrives via LDS broadcast.
// NO __syncthreads anywhere.
__launch_bounds__(256)
__global__ void kD(const float* __restrict__ q, const float* __restrict__ k,
                   const float* __restrict__ G, const float* __restrict__ S,
                   const float* __restrict__ kpre, float* __restrict__ out) {
    __shared__ __align__(16) float bufA[64*64];   // q rows, then k rows (per-wave slices)
    __shared__ __align__(16) float bufB[64*64];   // qg rows (per-wave slices)

    int t = threadIdx.x, w = t >> 6, lane = t & 63;
    int head = blockIdx.y, tile = blockIdx.x;     // 64 tiles of 64 rows
    long rowbase = (long)head*NN + (long)tile*64; // global row index of tile start

    float4* A4 = (float4*)&bufA[w*1024];

    // ---- stage own 16 q rows ----
    {
        const float4* qg4 = (const float4*)(q + (rowbase + w*16)*64);
#pragma unroll
        for (int c = 0; c < 4; ++c) A4[c*64 + lane] = qg4[c*64 + lane];
    }

    // ---- phase 1: qg[r][lane] = sum_kk q[r][kk] * G[kk][lane] ----
    float acc[16];
#pragma unroll
    for (int r = 0; r < 16; ++r) acc[r] = 0.f;
#pragma unroll
    for (int h = 0; h < 2; ++h) {
        float Gc[32];
#pragma unroll
        for (int kk = 0; kk < 32; ++kk) Gc[kk] = G[(h*32 + kk)*64 + lane];
#pragma unroll
        for (int kq = 0; kq < 8; ++kq) {
#pragma unroll
            for (int r = 0; r < 16; ++r) {
                float4 q4 = *(const float4*)&bufA[(w*16 + r)*64 + h*32 + kq*4]; // broadcast
                acc[r] += q4.x*Gc[kq*4+0] + q4.y*Gc[kq*4+1]
                        + q4.z*Gc[kq*4+2] + q4.w*Gc[kq*4+3];
            }
        }
    }
    // qg -> own LDS slice (needed as broadcast source in phase 4)
#pragma unroll
    for (int r = 0; r < 16; ++r) bufB[(w*16 + r)*64 + lane] = acc[r];

    // ---- restage own 16 k rows (overwrites own q slice; in-wave order preserved) ----
    {
        const float4* kg4 = (const float4*)(k + (rowbase + w*16)*64);
#pragma unroll
        for (int c = 0; c < 4; ++c) A4[c*64 + lane] = kg4[c*64 + lane];
    }

    // ---- group prefix: kpre + (odd waves) top-up from global k, no cross-wave LDS ----
    float pre = kpre[((long)head*128 + tile*2 + (w >> 1))*64 + lane];
    if (w & 1) {
        const float* kp = k + (rowbase + (w-1)*16)*64;
#pragma unroll
        for (int r = 0; r < 16; ++r) pre += kp[r*64 + lane];
    }

    // ---- cumsum + denominators ----
    float dinv[16];
#pragma unroll
    for (int r = 0; r < 16; ++r) {
        pre += bufA[(w*16 + r)*64 + lane];        // kcum[row][lane]
        float p = acc[r] * pre;                   // qg . kcum, partial per lane
#pragma unroll
        for (int o = 32; o; o >>= 1) p += __shfl_xor(p, o, 64);
        dinv[r] = __builtin_amdgcn_rcpf(p);
    }

    // ---- phase 4: out[r][lane] = dinv[r] * sum_kk qg[r][kk] * S[kk][lane] ----
    float o16[16];
#pragma unroll
    for (int r = 0; r < 16; ++r) o16[r] = 0.f;
#pragma unroll
    for (int h = 0; h < 2; ++h) {
        float Sc[32];
#pragma unroll
        for (int kk = 0; kk < 32; ++kk) Sc[kk] = S[(long)head*4096 + (h*32 + kk)*64 + lane];
#pragma unroll
        for (int kq = 0; kq < 8; ++kq) {
#pragma unroll
            for (int r = 0; r < 16; ++r) {
                float4 g4 = *(const float4*)&bufB[(w*16 + r)*64 + h*32 + kq*4]; // broadcast
                o16[r] += g4.x*Sc[kq*4+0] + g4.y*Sc[kq*4+1]
                        + g4.z*Sc[kq*4+2] + g4.w*Sc[kq*4+3];
            }
        }
    }
#pragma unroll
    for (int r = 0; r < 16; ++r)
        out[(rowbase + w*16 + r)*64 + lane] = o16[r] * dinv[r];
}

extern "C" void kernel_launch(void* const* d_in, const int* in_sizes, int n_in,
                              void* d_out, int out_size, void* d_ws, size_t ws_size,
                              hipStream_t stream) {
    (void)in_sizes; (void)n_in; (void)out_size; (void)ws_size;
    const float* q = (const float*)d_in[0];
    const float* k = (const float*)d_in[1];
    const float* v = (const float*)d_in[2];
    const float* P = (const float*)d_in[3];
    float* out = (float*)d_out;
    float* ws  = (float*)d_ws;

    float* G    = ws + OFF_G;
    float* S    = ws + OFF_S;
    float* gs   = ws + OFF_GS;
    float* kpre = ws + OFF_KP;

    hipMemsetAsync(S, 0, (size_t)64*4096*sizeof(float), stream);
    kA_gram<<<64, 64, 0, stream>>>(P, G);
    kB<<<dim3(16, 64), 256, 0, stream>>>(k, v, S, gs);
    kC<<<64, 256, 0, stream>>>(gs, kpre);
    kD<<<dim3(64, 64), 256, 0, stream>>>(q, k, G, S, kpre, out);
}